// Round 1
// 1562.078 us; speedup vs baseline: 1.2669x; 1.2669x over previous
//
#include <hip/hip_runtime.h>

#define TT 2048
#define BB 256
#define II 64
#define HH 128
#define CHP 16          // x/gx chunk depth in timesteps
#define GXS 532         // gx row stride in floats (slot = col*4 + gate, padded)

typedef __fp16 f16;
typedef __fp16 h2  __attribute__((ext_vector_type(2)));
typedef __fp16 v8h __attribute__((ext_vector_type(8)));
typedef float  v4f __attribute__((ext_vector_type(4)));

union HI { int i; h2 h; };
__device__ __forceinline__ h2  i2h(int v) { HI u; u.i = v; return u.h; }
__device__ __forceinline__ int h2i(h2 v)  { HI u; u.h = v; return u.i; }

__device__ __forceinline__ float fsig(float x) {
  return __builtin_amdgcn_rcpf(1.0f + __expf(-x));
}
__device__ __forceinline__ float ftanh(float x) {
  return 1.0f - 2.0f * __builtin_amdgcn_rcpf(1.0f + __expf(2.0f * x));
}

// Raw barrier: LDS-drain only; global loads/stores stay in flight.
__device__ __forceinline__ void bar_lgkm() {
  asm volatile("s_waitcnt lgkmcnt(0)\n\ts_barrier" ::: "memory");
}

// One block per batch row, 256 threads = 4 waves (1/SIMD). Latency-bound
// sequential recurrence: runtime = T * per-step critical path.
// This version: (1) x-projection precomputed per 16-step chunk via M=16
// timestep-packing MFMAs (reuses resident Wir/Wiz/Win B-frags) -> per-step
// MFMA 36 -> 24; (2) MFMA groups ordered r,n,z so the epilogue transcendental
// chain overlaps z issue; (3) CLS==0: h history streamed to global (f32,
// fire-and-forget), classifier in a second kernel -> wave-3 shuffle chain off
// the barrier path. CLS==1: in-loop classifier fallback (small workspace).
template <int CLS>
__global__ __launch_bounds__(256, 1) void gru_mfma(
    const float* __restrict__ x,
    const float* __restrict__ Wir, const float* __restrict__ Wiz, const float* __restrict__ Win,
    const float* __restrict__ bir, const float* __restrict__ biz, const float* __restrict__ bin_,
    const float* __restrict__ Whr, const float* __restrict__ Whz, const float* __restrict__ Whn,
    const float* __restrict__ bhn, const float* __restrict__ Wc,  const float* __restrict__ bc,
    float* __restrict__ hh, float* __restrict__ out)
{
  const int t = threadIdx.x, b = blockIdx.x;
  const int w = t >> 6;     // wave id
  const int l = t & 63;     // lane
  const int q = l >> 4;     // quad
  const int r = l & 15;

  __shared__ __attribute__((aligned(16))) f16   hbuf[2][HH];       // h state, dbuf
  __shared__ __attribute__((aligned(16))) f16   xch[2][CHP][72];   // x chunks (f16, A-layout)
  __shared__ __attribute__((aligned(16))) float gxb[2][CHP][GXS];  // gx = x@Wi + bi (f32), dbuf
  __shared__ float cpart[2][64];                                    // CLS==1 classifier partials

  // ---- resident B fragments: B[k=32kt+8q+j][n=32w+16ct+r] ----
  // kt 0..3 of br_/bz_ = Whr/Whz; kt 4..5 = Wir/Wiz (also reused by the
  // x-projection precompute). bnx_ = Win.
  v8h br_[6][2], bz_[6][2], bnh_[4][2], bnx_[2][2];
  for (int kt = 0; kt < 6; ++kt)
    for (int ct = 0; ct < 2; ++ct) {
      const int n = 32 * w + 16 * ct + r;
      v8h vr, vz;
      for (int j = 0; j < 8; ++j) {
        const int kg = 32 * kt + 8 * q + j;
        vr[j] = (f16)((kg < HH) ? Whr[kg * HH + n] : Wir[(kg - HH) * HH + n]);
        vz[j] = (f16)((kg < HH) ? Whz[kg * HH + n] : Wiz[(kg - HH) * HH + n]);
      }
      br_[kt][ct] = vr; bz_[kt][ct] = vz;
    }
  for (int kt = 0; kt < 4; ++kt)
    for (int ct = 0; ct < 2; ++ct) {
      const int n = 32 * w + 16 * ct + r;
      v8h v;
      for (int j = 0; j < 8; ++j) v[j] = (f16)Whn[(32 * kt + 8 * q + j) * HH + n];
      bnh_[kt][ct] = v;
    }
  for (int kt = 0; kt < 2; ++kt)
    for (int ct = 0; ct < 2; ++ct) {
      const int n = 32 * w + 16 * ct + r;
      v8h v;
      for (int j = 0; j < 8; ++j) v[j] = (f16)Win[(32 * kt + 8 * q + j) * HH + n];
      bnx_[kt][ct] = v;
    }

  float birc[2], bizc[2], binc[2], bhnc[2];
  for (int ct = 0; ct < 2; ++ct) {
    const int n = 32 * w + 16 * ct + r;
    birc[ct] = bir[n]; bizc[ct] = biz[n]; binc[ct] = bin_[n]; bhnc[ct] = bhn[n];
  }
  float wcA = 0.f, wcB = 0.f, bc0 = 0.f;
  if (CLS == 1) { wcA = Wc[32 * w + r]; wcB = Wc[32 * w + 16 + r]; bc0 = bc[0]; }

  // gx precompute: 16 timesteps packed into M; A[ts=l&15][k=8q+j (+32 per kt)];
  // C[ts=4q+j][col=l&15 of tile]. Bias folded in as accumulator init.
  auto precomp = [&](int pn, v8h ax0, v8h ax1) {
    #pragma unroll
    for (int ct = 0; ct < 2; ++ct) {
      v4f cr = {birc[ct], birc[ct], birc[ct], birc[ct]};
      v4f cz = {bizc[ct], bizc[ct], bizc[ct], bizc[ct]};
      v4f cn = {binc[ct], binc[ct], binc[ct], binc[ct]};
      cr = __builtin_amdgcn_mfma_f32_16x16x32_f16(ax0, br_[4][ct],  cr, 0, 0, 0);
      cz = __builtin_amdgcn_mfma_f32_16x16x32_f16(ax0, bz_[4][ct],  cz, 0, 0, 0);
      cn = __builtin_amdgcn_mfma_f32_16x16x32_f16(ax0, bnx_[0][ct], cn, 0, 0, 0);
      cr = __builtin_amdgcn_mfma_f32_16x16x32_f16(ax1, br_[5][ct],  cr, 0, 0, 0);
      cz = __builtin_amdgcn_mfma_f32_16x16x32_f16(ax1, bz_[5][ct],  cz, 0, 0, 0);
      cn = __builtin_amdgcn_mfma_f32_16x16x32_f16(ax1, bnx_[1][ct], cn, 0, 0, 0);
      const int col = 32 * w + 16 * ct + r;   // wave-local columns: no cross-wave dep
      #pragma unroll
      for (int j = 0; j < 4; ++j) {
        v4f pk; pk[0] = cr[j]; pk[1] = cz[j]; pk[2] = cn[j]; pk[3] = 0.f;
        *(v4f*)&gxb[pn][4 * q + j][col * 4] = pk;
      }
    }
  };

  // ---- prologue: x chunks 0,1 -> LDS; gx chunk 0 ----
  const int xrow = t >> 4, xcol = (t & 15) * 4;   // thread covers 4 f32 of one row
  float4 xr;
  {
    float4 xA = *(const float4*)(x + ((size_t)(0   + xrow) * BB + b) * II + xcol);
    float4 xB = *(const float4*)(x + ((size_t)(CHP + xrow) * BB + b) * II + xcol);
    if (t < HH) { hbuf[0][t] = (f16)0.f; hbuf[1][t] = (f16)0.f; }
    int2 pv;
    pv.x = h2i(__builtin_amdgcn_cvt_pkrtz(xA.x, xA.y));
    pv.y = h2i(__builtin_amdgcn_cvt_pkrtz(xA.z, xA.w));
    *(int2*)&xch[0][xrow][xcol] = pv;
    __syncthreads();
    {
      v8h a0x = *(const v8h*)&xch[0][r][8 * q];
      v8h a1x = *(const v8h*)&xch[0][r][32 + 8 * q];
      precomp(0, a0x, a1x);
    }
    pv.x = h2i(__builtin_amdgcn_cvt_pkrtz(xB.x, xB.y));
    pv.y = h2i(__builtin_amdgcn_cvt_pkrtz(xB.z, xB.w));
    *(int2*)&xch[1][xrow][xcol] = pv;
    __syncthreads();
  }

  // gx prefetch registers (step 0)
  v4f gp0 = *(const v4f*)&gxb[0][0][(32 * w + r) * 4];
  v4f gp1 = *(const v4f*)&gxb[0][0][(32 * w + 16 + r) * 4];

  v8h af[4] = {};            // non-(r==0) lanes stay zero forever
  float hst[2] = {0.f, 0.f};
  float* hpb = (CLS == 0) ? (hh + (size_t)b * HH + 32 * w + r) : nullptr;

  #pragma unroll 1
  for (int s = 0; s < TT; ++s) {
    const int cur = s & 1, nxt = cur ^ 1;
    const int sc = s & (CHP - 1), p = (s >> 4) & 1;
    const bool pc = (sc == 0) && (s + CHP < TT);

    // chunk boundary: issue A-frag reads for next chunk's gx precompute and
    // global loads for the chunk after that (15 steps of latency slack).
    v8h ax0 = {}, ax1 = {};
    if (pc) {
      ax0 = *(const v8h*)&xch[p ^ 1][r][8 * q];
      ax1 = *(const v8h*)&xch[p ^ 1][r][32 + 8 * q];
    }
    if (sc == 0 && s + 2 * CHP < TT) {
      xr = *(const float4*)(x + ((size_t)(s + 2 * CHP + xrow) * BB + b) * II + xcol);
    }

    // CLS==1: pick up previous step's classifier partials
    float cred = 0.f;
    if (CLS == 1 && w == 3 && s > 0) cred = cpart[nxt][l];

    // h A-frags (barrier-dependent; 4 reads, r==0 lanes)
    if (r == 0) {
      af[0] = *(const v8h*)&hbuf[cur][8 * q];
      af[1] = *(const v8h*)&hbuf[cur][32 + 8 * q];
      af[2] = *(const v8h*)&hbuf[cur][64 + 8 * q];
      af[3] = *(const v8h*)&hbuf[cur][96 + 8 * q];
    }

    // MFMA phase: K=128 (h only). Group order r -> n -> z so the epilogue's
    // sigmoid/tanh chain overlaps the z-group issue.
    v4f a0[2], a1[2], n0[2], n1[2], z0[2], z1[2];
    const v4f vz0 = {0.f, 0.f, 0.f, 0.f};
    #pragma unroll
    for (int ct = 0; ct < 2; ++ct) {
      a0[ct] = __builtin_amdgcn_mfma_f32_16x16x32_f16(af[0], br_[0][ct], vz0, 0, 0, 0);
      a1[ct] = __builtin_amdgcn_mfma_f32_16x16x32_f16(af[2], br_[2][ct], vz0, 0, 0, 0);
    }
    #pragma unroll
    for (int ct = 0; ct < 2; ++ct) {
      a0[ct] = __builtin_amdgcn_mfma_f32_16x16x32_f16(af[1], br_[1][ct], a0[ct], 0, 0, 0);
      a1[ct] = __builtin_amdgcn_mfma_f32_16x16x32_f16(af[3], br_[3][ct], a1[ct], 0, 0, 0);
    }
    #pragma unroll
    for (int ct = 0; ct < 2; ++ct) {
      n0[ct] = __builtin_amdgcn_mfma_f32_16x16x32_f16(af[0], bnh_[0][ct], vz0, 0, 0, 0);
      n1[ct] = __builtin_amdgcn_mfma_f32_16x16x32_f16(af[2], bnh_[2][ct], vz0, 0, 0, 0);
    }
    #pragma unroll
    for (int ct = 0; ct < 2; ++ct) {
      n0[ct] = __builtin_amdgcn_mfma_f32_16x16x32_f16(af[1], bnh_[1][ct], n0[ct], 0, 0, 0);
      n1[ct] = __builtin_amdgcn_mfma_f32_16x16x32_f16(af[3], bnh_[3][ct], n1[ct], 0, 0, 0);
    }
    #pragma unroll
    for (int ct = 0; ct < 2; ++ct) {
      z0[ct] = __builtin_amdgcn_mfma_f32_16x16x32_f16(af[0], bz_[0][ct], vz0, 0, 0, 0);
      z1[ct] = __builtin_amdgcn_mfma_f32_16x16x32_f16(af[2], bz_[2][ct], vz0, 0, 0, 0);
    }
    #pragma unroll
    for (int ct = 0; ct < 2; ++ct) {
      z0[ct] = __builtin_amdgcn_mfma_f32_16x16x32_f16(af[1], bz_[1][ct], z0[ct], 0, 0, 0);
      z1[ct] = __builtin_amdgcn_mfma_f32_16x16x32_f16(af[3], bz_[3][ct], z1[ct], 0, 0, 0);
    }

    // gx for THIS step (prefetched last step); prefetch next step's gx now
    // (barrier-independent, latency hides under the MFMA tail).
    const v4f g0 = gp0, g1 = gp1;
    {
      const int sn = s + 1;
      if (sn < TT) {
        const int pn2 = (sn >> 4) & 1, scn = sn & (CHP - 1);
        gp0 = *(const v4f*)&gxb[pn2][scn][(32 * w + r) * 4];
        gp1 = *(const v4f*)&gxb[pn2][scn][(32 * w + 16 + r) * 4];
      }
    }

    // epilogue: C row 0 = elem 0 of quad-0 lanes; col = 32w+16ct+r
    if (q == 0) {
      #pragma unroll
      for (int ct = 0; ct < 2; ++ct) {
        const v4f g = ct ? g1 : g0;            // {gxr, gxz, gxn, pad} incl. biases
        const float arS = a0[ct][0] + a1[ct][0] + g[0];
        const float anS = n0[ct][0] + n1[ct][0] + bhnc[ct];
        const float rr  = fsig(arS);
        const float nn  = ftanh(g[2] + rr * anS);
        const float azS = z0[ct][0] + z1[ct][0] + g[1];
        const float zz  = fsig(azS);
        hst[ct] = nn + zz * (hst[ct] - nn);
        hbuf[nxt][32 * w + 16 * ct + r] = (f16)hst[ct];
        if (CLS == 0) hpb[(size_t)s * (BB * HH) + 16 * ct] = hst[ct];  // fire-and-forget
      }
      if (CLS == 1) cpart[cur][16 * w + r] = hst[0] * wcA + hst[1] * wcB;
    }

    // CLS==1: finish previous step's classifier (overlaps with other waves)
    if (CLS == 1 && w == 3 && s > 0) {
      cred += __shfl_xor(cred, 1, 64);
      cred += __shfl_xor(cred, 2, 64);
      cred += __shfl_xor(cred, 4, 64);
      cred += __shfl_xor(cred, 8, 64);
      cred += __shfl_xor(cred, 16, 64);
      cred += __shfl_xor(cred, 32, 64);
      if (l == 0) out[(size_t)(s - 1) * BB + b] = fsig(cred + bc0);
    }

    // amortized x-projection for chunk c+1 (12 MFMAs/wave per 16 steps)
    if (pc) precomp(p ^ 1, ax0, ax1);

    // stage chunk c+2's x (loaded at this chunk's sc==0) into xch[p]
    if (sc == CHP - 1 && s + CHP + 1 < TT) {
      int2 pv;
      pv.x = h2i(__builtin_amdgcn_cvt_pkrtz(xr.x, xr.y));
      pv.y = h2i(__builtin_amdgcn_cvt_pkrtz(xr.z, xr.w));
      *(int2*)&xch[p][xrow][xcol] = pv;
    }

    bar_lgkm();
  }

  if (CLS == 1 && w == 3) {
    float cred = cpart[1][l];
    cred += __shfl_xor(cred, 1, 64);
    cred += __shfl_xor(cred, 2, 64);
    cred += __shfl_xor(cred, 4, 64);
    cred += __shfl_xor(cred, 8, 64);
    cred += __shfl_xor(cred, 16, 64);
    cred += __shfl_xor(cred, 32, 64);
    if (l == 0) out[(size_t)(TT - 1) * BB + b] = fsig(cred + bc0);
  }
}

// out[row] = sigmoid(dot(hh[row][:], Wc) + bc); row = t*BB + b.
// 4 threads per row (32 cols each), 64 rows/block, coalesced f32 reads.
__global__ __launch_bounds__(256) void gru_cls(
    const float* __restrict__ hh, const float* __restrict__ Wc,
    const float* __restrict__ bc, float* __restrict__ out)
{
  const int t  = threadIdx.x;
  const int g4 = t & 3;
  const size_t row = (size_t)blockIdx.x * 64 + (t >> 2);
  const float* hp = hh + row * HH + 32 * g4;
  const float* wp = Wc + 32 * g4;
  float acc = 0.f;
  #pragma unroll
  for (int i = 0; i < 8; ++i) {
    v4f h4 = *(const v4f*)(hp + 4 * i);
    v4f w4 = *(const v4f*)(wp + 4 * i);
    acc += h4[0] * w4[0] + h4[1] * w4[1] + h4[2] * w4[2] + h4[3] * w4[3];
  }
  acc += __shfl_xor(acc, 1, 64);
  acc += __shfl_xor(acc, 2, 64);
  if (g4 == 0) out[row] = fsig(acc + bc[0]);
}

extern "C" void kernel_launch(void* const* d_in, const int* in_sizes, int n_in,
                              void* d_out, int out_size, void* d_ws, size_t ws_size,
                              hipStream_t stream) {
  const float* x    = (const float*)d_in[0];
  const float* Wir  = (const float*)d_in[1];
  const float* Wiz  = (const float*)d_in[2];
  const float* Win  = (const float*)d_in[3];
  const float* bir  = (const float*)d_in[4];
  const float* biz  = (const float*)d_in[5];
  const float* bin_ = (const float*)d_in[6];
  const float* Whr  = (const float*)d_in[7];
  const float* Whz  = (const float*)d_in[8];
  const float* Whn  = (const float*)d_in[9];
  const float* bhn  = (const float*)d_in[10];
  const float* Wc   = (const float*)d_in[11];
  const float* bc   = (const float*)d_in[12];
  float* out = (float*)d_out;

  const size_t need = (size_t)TT * BB * HH * sizeof(float);  // 256 MiB h history
  if (d_ws != nullptr && ws_size >= need) {
    float* hh = (float*)d_ws;
    gru_mfma<0><<<dim3(BB), dim3(256), 0, stream>>>(
        x, Wir, Wiz, Win, bir, biz, bin_, Whr, Whz, Whn, bhn, Wc, bc, hh, out);
    gru_cls<<<dim3((TT * BB) / 64), dim3(256), 0, stream>>>(hh, Wc, bc, out);
  } else {
    gru_mfma<1><<<dim3(BB), dim3(256), 0, stream>>>(
        x, Wir, Wiz, Win, bir, biz, bin_, Whr, Whz, Whn, bhn, Wc, bc, nullptr, out);
  }
}

// Round 2
// 1326.090 us; speedup vs baseline: 1.4924x; 1.1780x over previous
//
#include <hip/hip_runtime.h>

#define TT 2048
#define BB 256
#define II 64
#define HH 128
#define CHP 16          // x/gx chunk depth in timesteps
#define GXS 532         // gx row stride in floats (slot = col*4 + gate, padded)

typedef __fp16 f16;
typedef __fp16 h2  __attribute__((ext_vector_type(2)));
typedef __fp16 v8h __attribute__((ext_vector_type(8)));
typedef float  v4f __attribute__((ext_vector_type(4)));

union HI { int i; h2 h; };
__device__ __forceinline__ h2  i2h(int v) { HI u; u.i = v; return u.h; }
__device__ __forceinline__ int h2i(h2 v)  { HI u; u.h = v; return u.i; }

__device__ __forceinline__ float fsig(float x) {
  return __builtin_amdgcn_rcpf(1.0f + __expf(-x));
}
__device__ __forceinline__ float ftanh(float x) {
  return 1.0f - 2.0f * __builtin_amdgcn_rcpf(1.0f + __expf(2.0f * x));
}

// Raw barrier: LDS-drain only; global loads/stores stay in flight.
__device__ __forceinline__ void bar_lgkm() {
  asm volatile("s_waitcnt lgkmcnt(0)\n\ts_barrier" ::: "memory");
}

// One block per batch row. NOW 512 threads = 8 waves = 2 waves/SIMD:
// per-wave work halved (12 MFMAs, one output col per q==0 lane) so the two
// waves sharing a SIMD co-issue -- VALU/LDS/waitcnt of one hides under the
// other's MFMA occupancy. Matrix-pipe floor per SIMD unchanged (24 MFMA).
// x-projection gx precomputed per 16-step chunk via timestep-packed MFMAs
// (reuses resident Wir/Wiz/Win B-frags). CLS==0: h history streamed to
// global, classifier in a second kernel. CLS==1: in-loop fallback.
template <int CLS>
__global__ __launch_bounds__(512, 1) void gru_mfma(
    const float* __restrict__ x,
    const float* __restrict__ Wir, const float* __restrict__ Wiz, const float* __restrict__ Win,
    const float* __restrict__ bir, const float* __restrict__ biz, const float* __restrict__ bin_,
    const float* __restrict__ Whr, const float* __restrict__ Whz, const float* __restrict__ Whn,
    const float* __restrict__ bhn, const float* __restrict__ Wc,  const float* __restrict__ bc,
    float* __restrict__ hh, float* __restrict__ out)
{
  const int t = threadIdx.x, b = blockIdx.x;
  const int w = t >> 6;     // wave id 0..7
  const int l = t & 63;     // lane
  const int q = l >> 4;     // quad
  const int r = l & 15;
  const int nc = 16 * w + r;   // this lane's output column

  __shared__ __attribute__((aligned(16))) f16   hbuf[2][HH];       // h state, dbuf
  __shared__ __attribute__((aligned(16))) f16   xch[2][CHP][72];   // x chunks (f16, A-layout)
  __shared__ __attribute__((aligned(16))) float gxb[2][CHP][GXS];  // gx = x@Wi + bi (f32), dbuf
  __shared__ float cpart[2][128];                                   // CLS==1 classifier partials

  // ---- resident B fragments: B[k=32kt+8q+j][n=nc] ----
  // kt 0..3 of br_/bz_ = Whr/Whz; kt 4..5 = Wir/Wiz (reused by gx precompute).
  v8h br_[6], bz_[6], bnh_[4], bnx_[2];
  for (int kt = 0; kt < 6; ++kt) {
    v8h vr, vz;
    for (int j = 0; j < 8; ++j) {
      const int kg = 32 * kt + 8 * q + j;
      vr[j] = (f16)((kg < HH) ? Whr[kg * HH + nc] : Wir[(kg - HH) * HH + nc]);
      vz[j] = (f16)((kg < HH) ? Whz[kg * HH + nc] : Wiz[(kg - HH) * HH + nc]);
    }
    br_[kt] = vr; bz_[kt] = vz;
  }
  for (int kt = 0; kt < 4; ++kt) {
    v8h v;
    for (int j = 0; j < 8; ++j) v[j] = (f16)Whn[(32 * kt + 8 * q + j) * HH + nc];
    bnh_[kt] = v;
  }
  for (int kt = 0; kt < 2; ++kt) {
    v8h v;
    for (int j = 0; j < 8; ++j) v[j] = (f16)Win[(32 * kt + 8 * q + j) * HH + nc];
    bnx_[kt] = v;
  }

  const float birc = bir[nc], bizc = biz[nc], binc = bin_[nc], bhnc = bhn[nc];
  float wc = 0.f, bc0 = 0.f;
  if (CLS == 1) { wc = Wc[nc]; bc0 = bc[0]; }

  // gx precompute: 16 timesteps packed into M; A[ts=r][k=8q+j (+32 for ax1)];
  // C[ts=4q+j][col=nc]. Bias folded in as accumulator init.
  auto precomp = [&](int pn, v8h ax0, v8h ax1) {
    v4f cr = {birc, birc, birc, birc};
    v4f cz = {bizc, bizc, bizc, bizc};
    v4f cn = {binc, binc, binc, binc};
    cr = __builtin_amdgcn_mfma_f32_16x16x32_f16(ax0, br_[4],  cr, 0, 0, 0);
    cz = __builtin_amdgcn_mfma_f32_16x16x32_f16(ax0, bz_[4],  cz, 0, 0, 0);
    cn = __builtin_amdgcn_mfma_f32_16x16x32_f16(ax0, bnx_[0], cn, 0, 0, 0);
    cr = __builtin_amdgcn_mfma_f32_16x16x32_f16(ax1, br_[5],  cr, 0, 0, 0);
    cz = __builtin_amdgcn_mfma_f32_16x16x32_f16(ax1, bz_[5],  cz, 0, 0, 0);
    cn = __builtin_amdgcn_mfma_f32_16x16x32_f16(ax1, bnx_[1], cn, 0, 0, 0);
    #pragma unroll
    for (int j = 0; j < 4; ++j) {
      v4f pk; pk[0] = cr[j]; pk[1] = cz[j]; pk[2] = cn[j]; pk[3] = 0.f;
      *(v4f*)&gxb[pn][4 * q + j][nc * 4] = pk;
    }
  };

  // ---- prologue: x chunks 0,1 -> LDS; gx chunk 0 ----
  const int xrow = t >> 5, xcol = (t & 31) * 2;   // thread covers 2 f32 of one row
  float2 xr;
  {
    float2 xA = *(const float2*)(x + ((size_t)(0   + xrow) * BB + b) * II + xcol);
    float2 xB = *(const float2*)(x + ((size_t)(CHP + xrow) * BB + b) * II + xcol);
    if (t < HH) { hbuf[0][t] = (f16)0.f; hbuf[1][t] = (f16)0.f; }
    *(int*)&xch[0][xrow][xcol] = h2i(__builtin_amdgcn_cvt_pkrtz(xA.x, xA.y));
    __syncthreads();
    {
      v8h a0x = *(const v8h*)&xch[0][r][8 * q];
      v8h a1x = *(const v8h*)&xch[0][r][32 + 8 * q];
      precomp(0, a0x, a1x);
    }
    *(int*)&xch[1][xrow][xcol] = h2i(__builtin_amdgcn_cvt_pkrtz(xB.x, xB.y));
    __syncthreads();
  }

  // gx prefetch register (step 0)
  v4f gp = *(const v4f*)&gxb[0][0][nc * 4];

  v8h af[4] = {};            // non-(r==0) lanes stay zero forever
  float hst = 0.f;
  float* hpb = (CLS == 0) ? (hh + (size_t)b * HH + nc) : nullptr;

  #pragma unroll 1
  for (int s = 0; s < TT; ++s) {
    const int cur = s & 1, nxt = cur ^ 1;
    const int sc = s & (CHP - 1), p = (s >> 4) & 1;
    const bool pc = (sc == 0) && (s + CHP < TT);

    // chunk boundary: A-frag reads for next chunk's gx precompute; global
    // loads for the chunk after that (15 steps of latency slack).
    v8h ax0 = {}, ax1 = {};
    if (pc) {
      ax0 = *(const v8h*)&xch[p ^ 1][r][8 * q];
      ax1 = *(const v8h*)&xch[p ^ 1][r][32 + 8 * q];
    }
    if (sc == 0 && s + 2 * CHP < TT) {
      xr = *(const float2*)(x + ((size_t)(s + 2 * CHP + xrow) * BB + b) * II + xcol);
    }

    // CLS==1: pick up previous step's classifier partials
    float cred = 0.f;
    if (CLS == 1 && w == 7 && s > 0) cred = cpart[nxt][l] + cpart[nxt][64 + l];

    // h A-frags (barrier-dependent; 4 reads, r==0 lanes)
    if (r == 0) {
      af[0] = *(const v8h*)&hbuf[cur][8 * q];
      af[1] = *(const v8h*)&hbuf[cur][32 + 8 * q];
      af[2] = *(const v8h*)&hbuf[cur][64 + 8 * q];
      af[3] = *(const v8h*)&hbuf[cur][96 + 8 * q];
    }

    // MFMA phase: K=128 (h only), 12 MFMAs, depth-2 chains.
    // Group order r -> n -> z so the epilogue transcendentals overlap z issue.
    const v4f vz0 = {0.f, 0.f, 0.f, 0.f};
    v4f ar0, ar1, an0, an1, az0, az1;
    ar0 = __builtin_amdgcn_mfma_f32_16x16x32_f16(af[0], br_[0], vz0, 0, 0, 0);
    ar1 = __builtin_amdgcn_mfma_f32_16x16x32_f16(af[2], br_[2], vz0, 0, 0, 0);
    ar0 = __builtin_amdgcn_mfma_f32_16x16x32_f16(af[1], br_[1], ar0, 0, 0, 0);
    ar1 = __builtin_amdgcn_mfma_f32_16x16x32_f16(af[3], br_[3], ar1, 0, 0, 0);
    an0 = __builtin_amdgcn_mfma_f32_16x16x32_f16(af[0], bnh_[0], vz0, 0, 0, 0);
    an1 = __builtin_amdgcn_mfma_f32_16x16x32_f16(af[2], bnh_[2], vz0, 0, 0, 0);
    an0 = __builtin_amdgcn_mfma_f32_16x16x32_f16(af[1], bnh_[1], an0, 0, 0, 0);
    an1 = __builtin_amdgcn_mfma_f32_16x16x32_f16(af[3], bnh_[3], an1, 0, 0, 0);
    az0 = __builtin_amdgcn_mfma_f32_16x16x32_f16(af[0], bz_[0], vz0, 0, 0, 0);
    az1 = __builtin_amdgcn_mfma_f32_16x16x32_f16(af[2], bz_[2], vz0, 0, 0, 0);
    az0 = __builtin_amdgcn_mfma_f32_16x16x32_f16(af[1], bz_[1], az0, 0, 0, 0);
    az1 = __builtin_amdgcn_mfma_f32_16x16x32_f16(af[3], bz_[3], az1, 0, 0, 0);

    // gx for THIS step (prefetched last step); prefetch next step's gx now
    // (barrier-independent, latency hides under the MFMA tail).
    const v4f g = gp;
    {
      const int sn = s + 1;
      if (sn < TT) {
        const int pn2 = (sn >> 4) & 1, scn = sn & (CHP - 1);
        gp = *(const v4f*)&gxb[pn2][scn][nc * 4];
      }
    }

    // epilogue: C row 0 = elem 0 of quad-0 lanes; col = nc
    if (q == 0) {
      const float arS = ar0[0] + ar1[0] + g[0];
      const float anS = an0[0] + an1[0] + bhnc;
      const float rr  = fsig(arS);
      const float nn  = ftanh(g[2] + rr * anS);
      const float azS = az0[0] + az1[0] + g[1];
      const float zz  = fsig(azS);
      hst = nn + zz * (hst - nn);
      hbuf[nxt][nc] = (f16)hst;
      if (CLS == 0) hpb[(size_t)s * (BB * HH)] = hst;   // fire-and-forget
      if (CLS == 1) cpart[cur][nc] = hst * wc;
    }

    // CLS==1: finish previous step's classifier (overlaps other waves' work)
    if (CLS == 1 && w == 7 && s > 0) {
      cred += __shfl_xor(cred, 1, 64);
      cred += __shfl_xor(cred, 2, 64);
      cred += __shfl_xor(cred, 4, 64);
      cred += __shfl_xor(cred, 8, 64);
      cred += __shfl_xor(cred, 16, 64);
      cred += __shfl_xor(cred, 32, 64);
      if (l == 0) out[(size_t)(s - 1) * BB + b] = fsig(cred + bc0);
    }

    // amortized x-projection for chunk c+1 (6 MFMAs/wave per 16 steps)
    if (pc) precomp(p ^ 1, ax0, ax1);

    // stage chunk c+2's x (loaded at this chunk's sc==0) into xch[p]
    if (sc == CHP - 1 && s + CHP + 1 < TT) {
      *(int*)&xch[p][xrow][xcol] = h2i(__builtin_amdgcn_cvt_pkrtz(xr.x, xr.y));
    }

    bar_lgkm();
  }

  if (CLS == 1 && w == 7) {
    float cred = cpart[1][l] + cpart[1][64 + l];
    cred += __shfl_xor(cred, 1, 64);
    cred += __shfl_xor(cred, 2, 64);
    cred += __shfl_xor(cred, 4, 64);
    cred += __shfl_xor(cred, 8, 64);
    cred += __shfl_xor(cred, 16, 64);
    cred += __shfl_xor(cred, 32, 64);
    if (l == 0) out[(size_t)(TT - 1) * BB + b] = fsig(cred + bc0);
  }
}

// out[row] = sigmoid(dot(hh[row][:], Wc) + bc); row = t*BB + b.
// 4 threads per row (32 cols each), 64 rows/block, coalesced f32 reads.
__global__ __launch_bounds__(256) void gru_cls(
    const float* __restrict__ hh, const float* __restrict__ Wc,
    const float* __restrict__ bc, float* __restrict__ out)
{
  const int t  = threadIdx.x;
  const int g4 = t & 3;
  const size_t row = (size_t)blockIdx.x * 64 + (t >> 2);
  const float* hp = hh + row * HH + 32 * g4;
  const float* wp = Wc + 32 * g4;
  float acc = 0.f;
  #pragma unroll
  for (int i = 0; i < 8; ++i) {
    v4f h4 = *(const v4f*)(hp + 4 * i);
    v4f w4 = *(const v4f*)(wp + 4 * i);
    acc += h4[0] * w4[0] + h4[1] * w4[1] + h4[2] * w4[2] + h4[3] * w4[3];
  }
  acc += __shfl_xor(acc, 1, 64);
  acc += __shfl_xor(acc, 2, 64);
  if (g4 == 0) out[row] = fsig(acc + bc[0]);
}

extern "C" void kernel_launch(void* const* d_in, const int* in_sizes, int n_in,
                              void* d_out, int out_size, void* d_ws, size_t ws_size,
                              hipStream_t stream) {
  const float* x    = (const float*)d_in[0];
  const float* Wir  = (const float*)d_in[1];
  const float* Wiz  = (const float*)d_in[2];
  const float* Win  = (const float*)d_in[3];
  const float* bir  = (const float*)d_in[4];
  const float* biz  = (const float*)d_in[5];
  const float* bin_ = (const float*)d_in[6];
  const float* Whr  = (const float*)d_in[7];
  const float* Whz  = (const float*)d_in[8];
  const float* Whn  = (const float*)d_in[9];
  const float* bhn  = (const float*)d_in[10];
  const float* Wc   = (const float*)d_in[11];
  const float* bc   = (const float*)d_in[12];
  float* out = (float*)d_out;

  const size_t need = (size_t)TT * BB * HH * sizeof(float);  // 256 MiB h history
  if (d_ws != nullptr && ws_size >= need) {
    float* hh = (float*)d_ws;
    gru_mfma<0><<<dim3(BB), dim3(512), 0, stream>>>(
        x, Wir, Wiz, Win, bir, biz, bin_, Whr, Whz, Whn, bhn, Wc, bc, hh, out);
    gru_cls<<<dim3((TT * BB) / 64), dim3(256), 0, stream>>>(hh, Wc, bc, out);
  } else {
    gru_mfma<1><<<dim3(BB), dim3(512), 0, stream>>>(
        x, Wir, Wiz, Win, bir, biz, bin_, Whr, Whz, Whn, bhn, Wc, bc, nullptr, out);
  }
}